// Round 1
// baseline (34506.610 us; speedup 1.0000x reference)
//
#include <hip/hip_runtime.h>
#include <hip/hip_cooperative_groups.h>
#include <math.h>

namespace cg = cooperative_groups;

#define DIM      1024
#define K_GATES  24
#define NMAX     512          // max Chebyshev terms per gate (|tau|<=~230 << 512)
#define QUAD_M   2048         // quadrature points for Bessel J_n
#define BBOUND   68.0f        // spectral-norm bound for GUE(1024), radius ~64 + margin
#define ROWS     8            // rows per block
#define NBLOCKS  128          // 128 * 8 = 1024 rows
#define NTHREADS 512          // 8 waves of 64

// ---------------------------------------------------------------- init state
// psi = pad(feature, 1024) / ||feature||, stored as float2 (re, im)
__global__ __launch_bounds__(1024) void init_state(const float* __restrict__ f,
                                                   int nfeat, float2* __restrict__ vec) {
    __shared__ float red[16];
    __shared__ float invn_s;
    int t = threadIdx.x;
    float v = (t < nfeat) ? f[t] : 0.f;
    float s = v * v;
    #pragma unroll
    for (int o = 1; o < 64; o <<= 1) s += __shfl_xor(s, o);
    if ((t & 63) == 0) red[t >> 6] = s;
    __syncthreads();
    if (t == 0) {
        float tot = 0.f;
        for (int i = 0; i < 16; i++) tot += red[i];
        invn_s = 1.0f / sqrtf(tot);
    }
    __syncthreads();
    vec[t] = make_float2(v * invn_s, 0.f);
}

// ---------------------------------------------------------------- Bessel coefs
// c_n(k) = (n==0?1:2) * (-i)^n * J_n(tau_k),  tau_k = theta_k * BBOUND
// J_n(x) = (1/2pi) \int_0^{2pi} cos(n p - x sin p) dp  (trapezoid, fp64, spectral)
__global__ __launch_bounds__(256) void bessel_coef(const float* __restrict__ theta,
                                                   float2* __restrict__ coefs) {
    int n = blockIdx.x;   // 0..NMAX-1
    int k = blockIdx.y;   // 0..K_GATES-1
    double tau = (double)theta[k] * (double)BBOUND;
    int t = threadIdx.x;  // 256
    double acc = 0.0;
    #pragma unroll
    for (int i = 0; i < QUAD_M / 256; i++) {
        int j = t + 256 * i;
        double phi = (2.0 * M_PI / (double)QUAD_M) * (double)j;
        acc += cos((double)n * phi - tau * sin(phi));
    }
    #pragma unroll
    for (int o = 1; o < 64; o <<= 1) acc += __shfl_xor(acc, o);
    __shared__ double red[4];
    if ((t & 63) == 0) red[t >> 6] = acc;
    __syncthreads();
    if (t == 0) {
        double J = (red[0] + red[1] + red[2] + red[3]) / (double)QUAD_M;
        double f = (n == 0) ? 1.0 : 2.0;
        float cr = 0.f, cim = 0.f;
        switch (n & 3) {                 // (-i)^n
            case 0: cr  =  (float)(f * J); break;
            case 1: cim = -(float)(f * J); break;
            case 2: cr  = -(float)(f * J); break;
            case 3: cim =  (float)(f * J); break;
        }
        coefs[k * NMAX + n] = make_float2(cr, cim);
    }
}

// ---------------------------------------------------------------- truncation
__global__ __launch_bounds__(NMAX) void trunc_len(const float2* __restrict__ coefs,
                                                  int* __restrict__ nterm) {
    int k = blockIdx.x;
    int t = threadIdx.x;  // 512
    float2 c = coefs[k * NMAX + t];
    float mag = fabsf(c.x) + fabsf(c.y);
    int myn = (mag > 2e-8f) ? t : 0;
    #pragma unroll
    for (int o = 1; o < 64; o <<= 1) myn = max(myn, __shfl_xor(myn, o));
    __shared__ int red[8];
    if ((t & 63) == 0) red[t >> 6] = myn;
    __syncthreads();
    if (t == 0) {
        int m = 1;
        for (int i = 0; i < 8; i++) m = max(m, red[i]);
        nterm[k] = min(m, NMAX - 1);
    }
}

// ---------------------------------------------------------------- main kernel
// y = Gtilde_row . x   (complex dot over 1024 elems, one wave per row)
__device__ __forceinline__ float2 matvec_row(const float2* __restrict__ x,
                                             const float2* __restrict__ grow,
                                             int lane) {
    const float4* x4 = (const float4*)x;     // 2 complex per float4
    const float4* g4 = (const float4*)grow;
    float sre = 0.f, sim = 0.f;
    #pragma unroll
    for (int m = 0; m < 8; m++) {
        int idx = lane + 64 * m;             // 512 float4 = 1024 complex
        float4 xv = x4[idx];
        float4 gv = g4[idx];
        sre += gv.x * xv.x - gv.y * xv.y + gv.z * xv.z - gv.w * xv.w;
        sim += gv.x * xv.y + gv.y * xv.x + gv.z * xv.w + gv.w * xv.z;
    }
    #pragma unroll
    for (int o = 1; o < 64; o <<= 1) {
        sre += __shfl_xor(sre, o);
        sim += __shfl_xor(sim, o);
    }
    return make_float2(sre, sim);
}

__global__ __launch_bounds__(NTHREADS) void evolve(const float* __restrict__ gre,
                                                   const float* __restrict__ gim,
                                                   float2* __restrict__ vec,
                                                   const float2* __restrict__ coefs,
                                                   const int* __restrict__ nterm,
                                                   float* __restrict__ out) {
    cg::grid_group grid = cg::this_grid();
    __shared__ float2 Gs[ROWS * DIM];        // 64 KiB: this block's 8 rows of Gtilde
    const int t = threadIdx.x, b = blockIdx.x;
    const int wave = t >> 6, lane = t & 63;
    const int r0 = b * ROWS;
    const int r = r0 + wave;                 // this wave's row
    const float hB = 0.5f / BBOUND;

    int is = 0, i1 = 1, i2 = 2, ia = 3;      // buffer indices: state, u, u, acc

    for (int k = 0; k < K_GATES; k++) {
        const float* R = gre + (size_t)k * DIM * DIM;
        const float* I = gim + (size_t)k * DIM * DIM;

        // ---- stage Gtilde = ((R+R^T)/2 + i (I-I^T)/2)/B into LDS ----
        // pass A: column panel R[:, r0:r0+8], I[:, r0:r0+8] (64B/row, line-efficient)
        #pragma unroll
        for (int half = 0; half < 2; half++) {
            int tt = t + half * 512;
            const float4* Rc = (const float4*)(R + (size_t)tt * DIM + r0);
            const float4* Ic = (const float4*)(I + (size_t)tt * DIM + r0);
            float4 ra = Rc[0], rb = Rc[1];
            float4 iaa = Ic[0], ib = Ic[1];
            Gs[0 * DIM + tt] = make_float2(hB * ra.x, -hB * iaa.x);
            Gs[1 * DIM + tt] = make_float2(hB * ra.y, -hB * iaa.y);
            Gs[2 * DIM + tt] = make_float2(hB * ra.z, -hB * iaa.z);
            Gs[3 * DIM + tt] = make_float2(hB * ra.w, -hB * iaa.w);
            Gs[4 * DIM + tt] = make_float2(hB * rb.x, -hB * ib.x);
            Gs[5 * DIM + tt] = make_float2(hB * rb.y, -hB * ib.y);
            Gs[6 * DIM + tt] = make_float2(hB * rb.z, -hB * ib.z);
            Gs[7 * DIM + tt] = make_float2(hB * rb.w, -hB * ib.w);
        }
        __syncthreads();
        // pass B: row panel (coalesced), accumulate into LDS
        {
            const float2* Rr = (const float2*)(R + (size_t)r * DIM);
            const float2* Ir = (const float2*)(I + (size_t)r * DIM);
            float4* G4 = (float4*)(Gs + wave * DIM);
            #pragma unroll
            for (int m = 0; m < 8; m++) {
                int idx = lane + 64 * m;
                float2 rv = Rr[idx], iv = Ir[idx];
                float4 g = G4[idx];
                g.x += hB * rv.x; g.y += hB * iv.x;
                g.z += hB * rv.y; g.w += hB * iv.y;
                G4[idx] = g;
            }
        }
        __syncthreads();

        const int N = nterm[k];
        const float2* C = coefs + k * NMAX;

        // ---- n = 1: u1 = Gt*s ; acc = c0*s + c1*u1 ----
        {
            float2 w = matvec_row(vec + is * DIM, Gs + wave * DIM, lane);
            if (lane == 0) {
                float2 c0 = C[0], c1 = C[1];
                float2 s = vec[is * DIM + r];
                vec[i1 * DIM + r] = w;
                float2 a;
                a.x = c0.x * s.x - c0.y * s.y + c1.x * w.x - c1.y * w.y;
                a.y = c0.x * s.y + c0.y * s.x + c1.x * w.y + c1.y * w.x;
                vec[ia * DIM + r] = a;
            }
        }
        grid.sync();

        // ---- n = 2..N: u_n = 2 Gt u_{n-1} - u_{n-2}; acc += c_n u_n ----
        int oldb = is, curb = i1, nxtb = i2;
        for (int n = 2; n <= N; n++) {
            float2 w = matvec_row(vec + curb * DIM, Gs + wave * DIM, lane);
            if (lane == 0) {
                float2 uo = vec[oldb * DIM + r];
                float2 tt = make_float2(2.f * w.x - uo.x, 2.f * w.y - uo.y);
                vec[nxtb * DIM + r] = tt;
                float2 cn = C[n];
                float2 a = vec[ia * DIM + r];
                a.x += cn.x * tt.x - cn.y * tt.y;
                a.y += cn.x * tt.y + cn.y * tt.x;
                vec[ia * DIM + r] = a;
            }
            grid.sync();
            int tmp = oldb; oldb = curb; curb = nxtb; nxtb = tmp;
        }

        // new state = acc; recycle old state buffer as next acc
        int tmp = is; is = ia; ia = tmp;
    }

    // probs = |psi|^2
    if (t < ROWS) {
        float2 s = vec[is * DIM + r0 + t];
        out[r0 + t] = s.x * s.x + s.y * s.y;
    }
}

// ---------------------------------------------------------------- launch
extern "C" void kernel_launch(void* const* d_in, const int* in_sizes, int n_in,
                              void* d_out, int out_size, void* d_ws, size_t ws_size,
                              hipStream_t stream) {
    const float* feat  = (const float*)d_in[0];   // 1000
    const float* theta = (const float*)d_in[1];   // 24
    const float* gre   = (const float*)d_in[2];   // 24*1024*1024
    const float* gim   = (const float*)d_in[3];

    // ws layout: vec[4][1024] float2 | coefs[24][512] float2 | nterm[24] int
    float2* vec   = (float2*)d_ws;
    float2* coefs = (float2*)((char*)d_ws + 4 * DIM * sizeof(float2));
    int*    nterm = (int*)((char*)d_ws + 4 * DIM * sizeof(float2)
                           + K_GATES * NMAX * sizeof(float2));
    float* outp = (float*)d_out;

    init_state<<<1, 1024, 0, stream>>>(feat, in_sizes[0], vec);
    bessel_coef<<<dim3(NMAX, K_GATES), 256, 0, stream>>>(theta, coefs);
    trunc_len<<<K_GATES, NMAX, 0, stream>>>(coefs, nterm);

    void* args[] = {(void*)&gre, (void*)&gim, (void*)&vec,
                    (void*)&coefs, (void*)&nterm, (void*)&outp};
    hipLaunchCooperativeKernel((void*)evolve, dim3(NBLOCKS), dim3(NTHREADS),
                               args, 0, stream);
}

// Round 2
// 6498.646 us; speedup vs baseline: 5.3098x; 5.3098x over previous
//
#include <hip/hip_runtime.h>
#include <math.h>

#define DIM      1024
#define K_GATES  24
#define NMAX     512          // max Chebyshev terms per gate
#define QUAD_M   2048         // quadrature points for Bessel J_n
#define BBOUND   66.0f        // spectral bound: GUE radius 64 + 3% margin
#define ROWS     16           // rows per block
#define NBLOCKS  64           // 64 * 16 = 1024 rows
#define NTHREADS 1024         // 16 waves of 64

// ---------------- coherent (agent-scope) 8-byte load/store: sc0 sc1, no fences
__device__ __forceinline__ float2 cohLoad(const float2* p) {
    unsigned long long v = __hip_atomic_load((const unsigned long long*)p,
                                             __ATOMIC_RELAXED, __HIP_MEMORY_SCOPE_AGENT);
    union { unsigned long long u; float2 f; } c; c.u = v; return c.f;
}
__device__ __forceinline__ void cohStore(float2* p, float2 val) {
    union { unsigned long long u; float2 f; } c; c.f = val;
    __hip_atomic_store((unsigned long long*)p, c.u,
                       __ATOMIC_RELAXED, __HIP_MEMORY_SCOPE_AGENT);
}

// ---------------------------------------------------------------- init state
// psi = pad(feature, 1024) / ||feature||; also zero the barrier counter
__global__ __launch_bounds__(1024) void init_state(const float* __restrict__ f,
                                                   int nfeat, float2* __restrict__ xbuf,
                                                   unsigned int* __restrict__ bar) {
    __shared__ float red[16];
    __shared__ float invn_s;
    int t = threadIdx.x;
    float v = (t < nfeat) ? f[t] : 0.f;
    float s = v * v;
    #pragma unroll
    for (int o = 1; o < 64; o <<= 1) s += __shfl_xor(s, o);
    if ((t & 63) == 0) red[t >> 6] = s;
    __syncthreads();
    if (t == 0) {
        float tot = 0.f;
        for (int i = 0; i < 16; i++) tot += red[i];
        invn_s = 1.0f / sqrtf(tot);
        *bar = 0u;
    }
    __syncthreads();
    xbuf[t] = make_float2(v * invn_s, 0.f);
}

// ---------------------------------------------------------------- Bessel coefs
// c_n(k) = (n==0?1:2) * (-i)^n * J_n(tau_k),  tau_k = theta_k * BBOUND
__global__ __launch_bounds__(256) void bessel_coef(const float* __restrict__ theta,
                                                   float2* __restrict__ coefs) {
    int n = blockIdx.x;   // 0..NMAX-1
    int k = blockIdx.y;   // 0..K_GATES-1
    double tau = (double)theta[k] * (double)BBOUND;
    int t = threadIdx.x;  // 256
    double acc = 0.0;
    #pragma unroll
    for (int i = 0; i < QUAD_M / 256; i++) {
        int j = t + 256 * i;
        double phi = (2.0 * M_PI / (double)QUAD_M) * (double)j;
        acc += cos((double)n * phi - tau * sin(phi));
    }
    #pragma unroll
    for (int o = 1; o < 64; o <<= 1) acc += __shfl_xor(acc, o);
    __shared__ double red[4];
    if ((t & 63) == 0) red[t >> 6] = acc;
    __syncthreads();
    if (t == 0) {
        double J = (red[0] + red[1] + red[2] + red[3]) / (double)QUAD_M;
        double f = (n == 0) ? 1.0 : 2.0;
        float cr = 0.f, cim = 0.f;
        switch (n & 3) {                 // (-i)^n
            case 0: cr  =  (float)(f * J); break;
            case 1: cim = -(float)(f * J); break;
            case 2: cr  = -(float)(f * J); break;
            case 3: cim =  (float)(f * J); break;
        }
        coefs[k * NMAX + n] = make_float2(cr, cim);
    }
}

// ---------------------------------------------------------------- truncation
__global__ __launch_bounds__(NMAX) void trunc_len(const float2* __restrict__ coefs,
                                                  int* __restrict__ nterm) {
    int k = blockIdx.x;
    int t = threadIdx.x;  // 512
    float2 c = coefs[k * NMAX + t];
    float mag = fabsf(c.x) + fabsf(c.y);
    int myn = (mag > 5e-7f) ? t : 0;   // 18x absmax margin -> looser cutoff
    #pragma unroll
    for (int o = 1; o < 64; o <<= 1) myn = max(myn, __shfl_xor(myn, o));
    __shared__ int red[8];
    if ((t & 63) == 0) red[t >> 6] = myn;
    __syncthreads();
    if (t == 0) {
        int m = 1;
        for (int i = 0; i < 8; i++) m = max(m, red[i]);
        nterm[k] = min(m, NMAX - 1);
    }
}

// ---------------------------------------------------------------- main kernel
__global__ __launch_bounds__(NTHREADS) void evolve(const float* __restrict__ gre,
                                                   const float* __restrict__ gim,
                                                   float2* __restrict__ xbuf,   // [2][DIM]
                                                   const float2* __restrict__ coefs,
                                                   const int* __restrict__ nterm,
                                                   unsigned int* __restrict__ bar,
                                                   float* __restrict__ out) {
    __shared__ float2 Gs[ROWS * DIM];        // 128 KiB: this block's 16 rows of Gtilde
    __shared__ float2 xs[DIM];               // 8 KiB: staged Chebyshev vector
    const int t = threadIdx.x, b = blockIdx.x;
    const int wave = t >> 6, lane = t & 63;
    const int r0 = b * ROWS;
    const int r = r0 + wave;                 // this wave's row (global component idx)
    const float hB = 0.5f / BBOUND;

    int cur = 0;                             // ping-pong parity of xbuf
    int eps = 0;                             // barrier epoch
    float2 acc = make_float2(0.f, 0.f);

    // hand-rolled grid barrier: relaxed agent atomics; __syncthreads drains vmcnt
    // so each block's coherent stores are retired before its arrival increment.
    auto gbar = [&]() {
        eps++;
        __syncthreads();
        if (t == 0) {
            __hip_atomic_fetch_add(bar, 1u, __ATOMIC_RELAXED, __HIP_MEMORY_SCOPE_AGENT);
            unsigned tgt = (unsigned)eps * NBLOCKS;
            while (__hip_atomic_load(bar, __ATOMIC_RELAXED, __HIP_MEMORY_SCOPE_AGENT) < tgt)
                __builtin_amdgcn_s_sleep(4);
        }
        __syncthreads();
    };

    for (int k = 0; k < K_GATES; k++) {
        const float* R = gre + (size_t)k * DIM * DIM;
        const float* I = gim + (size_t)k * DIM * DIM;

        // ---- stage Gtilde = ((R+R^T)/2 + i (I-I^T)/2)/B into LDS ----
        // pass A: column panel R[:, r0:r0+16], I[:, r0:r0+16] (64 B per row)
        {
            const float4* Rc = (const float4*)(R + (size_t)t * DIM + r0);
            const float4* Ic = (const float4*)(I + (size_t)t * DIM + r0);
            float4 ra0 = Rc[0], ra1 = Rc[1], ra2 = Rc[2], ra3 = Rc[3];
            float4 ia0 = Ic[0], ia1 = Ic[1], ia2 = Ic[2], ia3 = Ic[3];
            Gs[ 0 * DIM + t] = make_float2(hB * ra0.x, -hB * ia0.x);
            Gs[ 1 * DIM + t] = make_float2(hB * ra0.y, -hB * ia0.y);
            Gs[ 2 * DIM + t] = make_float2(hB * ra0.z, -hB * ia0.z);
            Gs[ 3 * DIM + t] = make_float2(hB * ra0.w, -hB * ia0.w);
            Gs[ 4 * DIM + t] = make_float2(hB * ra1.x, -hB * ia1.x);
            Gs[ 5 * DIM + t] = make_float2(hB * ra1.y, -hB * ia1.y);
            Gs[ 6 * DIM + t] = make_float2(hB * ra1.z, -hB * ia1.z);
            Gs[ 7 * DIM + t] = make_float2(hB * ra1.w, -hB * ia1.w);
            Gs[ 8 * DIM + t] = make_float2(hB * ra2.x, -hB * ia2.x);
            Gs[ 9 * DIM + t] = make_float2(hB * ra2.y, -hB * ia2.y);
            Gs[10 * DIM + t] = make_float2(hB * ra2.z, -hB * ia2.z);
            Gs[11 * DIM + t] = make_float2(hB * ra2.w, -hB * ia2.w);
            Gs[12 * DIM + t] = make_float2(hB * ra3.x, -hB * ia3.x);
            Gs[13 * DIM + t] = make_float2(hB * ra3.y, -hB * ia3.y);
            Gs[14 * DIM + t] = make_float2(hB * ra3.z, -hB * ia3.z);
            Gs[15 * DIM + t] = make_float2(hB * ra3.w, -hB * ia3.w);
        }
        __syncthreads();
        // pass B: row panel (coalesced), accumulate into LDS
        {
            const float4* Rr = (const float4*)(R + (size_t)r * DIM);
            const float4* Ir = (const float4*)(I + (size_t)r * DIM);
            float4* G4 = (float4*)(Gs + (size_t)wave * DIM);
            #pragma unroll
            for (int m = 0; m < 4; m++) {
                int i4 = lane + 64 * m;          // 256 float4 = 1024 floats
                float4 rv = Rr[i4], iv = Ir[i4];
                float4 g0 = G4[2 * i4], g1 = G4[2 * i4 + 1];
                g0.x += hB * rv.x; g0.y += hB * iv.x;
                g0.z += hB * rv.y; g0.w += hB * iv.y;
                g1.x += hB * rv.z; g1.y += hB * iv.z;
                g1.z += hB * rv.w; g1.w += hB * iv.w;
                G4[2 * i4] = g0; G4[2 * i4 + 1] = g1;
            }
        }
        __syncthreads();

        const int N = nterm[k];
        const float2* C = coefs + (size_t)k * NMAX;

        float2 t_prev, t_cur;
        bool first = true;

        for (int n = 1; n <= N; n++) {
            // stage x (coherent read-through) into LDS
            xs[t] = cohLoad(&xbuf[cur * DIM + t]);
            __syncthreads();

            // w = Gtilde_row . x  (complex dot over 1024, one wave per row)
            float sre = 0.f, sim = 0.f;
            {
                const float4* x4 = (const float4*)xs;
                const float4* g4 = (const float4*)(Gs + (size_t)wave * DIM);
                #pragma unroll
                for (int m = 0; m < 8; m++) {
                    int idx = lane + 64 * m;     // 512 float4 = 1024 complex
                    float4 xv = x4[idx];
                    float4 gv = g4[idx];
                    sre += gv.x * xv.x - gv.y * xv.y + gv.z * xv.z - gv.w * xv.w;
                    sim += gv.x * xv.y + gv.y * xv.x + gv.z * xv.w + gv.w * xv.z;
                }
                #pragma unroll
                for (int o = 1; o < 64; o <<= 1) {
                    sre += __shfl_xor(sre, o);
                    sim += __shfl_xor(sim, o);
                }
            }
            float2 w = make_float2(sre, sim);

            float2 t_next;
            if (first) {
                t_prev = xs[r];                  // T_0 = psi
                t_next = w;                      // T_1 = Gt psi
                float2 c0 = C[0], c1 = C[1];
                acc.x = c0.x * t_prev.x - c0.y * t_prev.y + c1.x * w.x - c1.y * w.y;
                acc.y = c0.x * t_prev.y + c0.y * t_prev.x + c1.x * w.y + c1.y * w.x;
                first = false;
            } else {
                t_next = make_float2(2.f * w.x - t_prev.x, 2.f * w.y - t_prev.y);
                float2 cn = C[n];
                acc.x += cn.x * t_next.x - cn.y * t_next.y;
                acc.y += cn.x * t_next.y + cn.y * t_next.x;
                t_prev = t_cur;
            }
            t_cur = t_next;

            if (lane == 0) cohStore(&xbuf[(cur ^ 1) * DIM + r], t_next);
            cur ^= 1;
            gbar();
        }

        // epilogue: new psi = acc, publish for next gate's staging
        if (lane == 0) cohStore(&xbuf[(cur ^ 1) * DIM + r], acc);
        cur ^= 1;
        gbar();
    }

    // probs = |psi|^2 (acc holds this wave's row of the final state)
    if (lane == 0) out[r] = acc.x * acc.x + acc.y * acc.y;
}

// ---------------------------------------------------------------- launch
extern "C" void kernel_launch(void* const* d_in, const int* in_sizes, int n_in,
                              void* d_out, int out_size, void* d_ws, size_t ws_size,
                              hipStream_t stream) {
    const float* feat  = (const float*)d_in[0];   // 1000
    const float* theta = (const float*)d_in[1];   // 24
    const float* gre   = (const float*)d_in[2];   // 24*1024*1024
    const float* gim   = (const float*)d_in[3];

    // ws layout: xbuf[2][1024] float2 | coefs[24][512] float2 | nterm[24] int | bar
    char* base = (char*)d_ws;
    float2*       xbuf  = (float2*)base;
    float2*       coefs = (float2*)(base + 2 * DIM * sizeof(float2));
    int*          nterm = (int*)(base + 2 * DIM * sizeof(float2)
                                 + K_GATES * NMAX * sizeof(float2));
    unsigned int* bar   = (unsigned int*)(base + 2 * DIM * sizeof(float2)
                                          + K_GATES * NMAX * sizeof(float2)
                                          + K_GATES * sizeof(int));
    float* outp = (float*)d_out;

    init_state<<<1, 1024, 0, stream>>>(feat, in_sizes[0], xbuf, bar);
    bessel_coef<<<dim3(NMAX, K_GATES), 256, 0, stream>>>(theta, coefs);
    trunc_len<<<K_GATES, NMAX, 0, stream>>>(coefs, nterm);

    void* args[] = {(void*)&gre, (void*)&gim, (void*)&xbuf,
                    (void*)&coefs, (void*)&nterm, (void*)&bar, (void*)&outp};
    hipLaunchCooperativeKernel((void*)evolve, dim3(NBLOCKS), dim3(NTHREADS),
                               args, 0, stream);
}